// Round 4
// baseline (309.919 us; speedup 1.0000x reference)
//
#include <hip/hip_runtime.h>
#include <math.h>

// 10-qubit real-amplitude circuit simulator, batch 16384, depth 8.
// Layout: 8 lanes per batch element (index bits [2:0] = lane&7),
//         64 x float2 (=128 scalars) per lane (index bits [9:3] = scalar reg).
// Qubit q <-> index bit (9-q): q0..q6 -> reg bits 6..0 ; q7,q8,q9 -> lane 2,1,0.
//
// Per layer (vs round-2 version):
//  - 6 reg-reg CNOTs: folded into RY(q0)'s operand addressing via the
//    compile-time permutation phi (0 instructions).
//  - 3 cross-lane CNOTs ((6,7),(8,9),(7,8)): composed into ONE ds_bpermute
//    per scalar (different source map for even/odd scalar regs).
//  - RY gates: float2 packed math -> v_pk_fma_f32.

typedef float v2f __attribute__((ext_vector_type(2)));

// ---- cross-lane helpers -------------------------------------------------
template<int CTRL>
__device__ __forceinline__ float dpp_mov(float x) {
  int i = __builtin_bit_cast(int, x);
  i = __builtin_amdgcn_update_dpp(i, i, CTRL, 0xf, 0xf, true);
  return __builtin_bit_cast(float, i);
}
// lane ^ 1 : quad_perm [1,0,3,2]
__device__ __forceinline__ float xl1(float x) { return dpp_mov<0xB1>(x); }
// lane ^ 2 : quad_perm [2,3,0,1]
__device__ __forceinline__ float xl2(float x) { return dpp_mov<0x4E>(x); }
// lane ^ 4 : ds_swizzle BitMode xor=4
__device__ __forceinline__ float xl4(float x) {
  int i = __builtin_bit_cast(int, x);
  i = __builtin_amdgcn_ds_swizzle(i, 0x101F);
  return __builtin_bit_cast(float, i);
}
__device__ __forceinline__ float bperm(int addr, float x) {
  int i = __builtin_amdgcn_ds_bpermute(addr, __builtin_bit_cast(int, x));
  return __builtin_bit_cast(float, i);
}
__device__ __forceinline__ float red8(float x) {
  x += xl1(x); x += xl2(x); x += xl4(x); return x;
}

// ---- compile-time read-permutation of the 6 register CNOTs --------------
// Time order: A(b6->b5) B(b4->b3) C(b2->b1) D(b5->b4) E(b3->b2) F(b1->b0).
// Read map after all six: s_after[j] = s_before[A(B(C(D(E(F(j))))))].
__host__ __device__ constexpr int phi(int j) {
  if (j & 2)  j ^= 1;    // F
  if (j & 8)  j ^= 4;    // E
  if (j & 32) j ^= 16;   // D
  if (j & 4)  j ^= 2;    // C
  if (j & 16) j ^= 8;    // B
  if (j & 64) j ^= 32;   // A
  return j;
}

// ---- RY on a register-bit qubit with M = 2*Mw (packed) ------------------
template<int Mw>
__device__ __forceinline__ void ry_w(v2f* w, v2f cc, v2f ss) {
  #pragma unroll
  for (int u = 0; u < 64; ++u) {
    if ((u & Mw) == 0) {
      v2f a = w[u], b = w[u + Mw];
      w[u]      = cc * a - ss * b;
      w[u + Mw] = ss * a + cc * b;
    }
  }
}

// ---- one level of the sum/diff tree -------------------------------------
template<int L2>
__device__ __forceinline__ float tree_level(float* t) {
  float a = 0.f, b = 0.f;
  #pragma unroll
  for (int j = 0; j < L2; ++j) {
    float e = t[2 * j], o = t[2 * j + 1];
    if (j & 1) b += e - o; else a += e - o;
    t[j] = e + o;
  }
  return a + b;
}

__global__ __launch_bounds__(256) void circuit_kernel(
    const float* __restrict__ x, const float* __restrict__ params,
    float* __restrict__ out) {
  __shared__ float stage[4][8][392];
  __shared__ float csh[160];  // cos/sin of pi*tanh(param)/2, [l*20 + 2q {+1}]

  const int tid  = threadIdx.x;
  const int wv   = tid >> 6;
  const int lane = tid & 63;
  const int g    = lane >> 3;
  const int l3   = lane & 7;
  const long elemBase = (long)blockIdx.x * 32 + (long)wv * 8;
  const long elem     = elemBase + g;

  if (tid < 80) {
    float th = 1.57079632679489662f * tanhf(params[tid]);  // (pi*tanh)/2
    csh[2 * tid]     = cosf(th);
    csh[2 * tid + 1] = sinf(th);
  }

  // bpermute source addresses for the fused cross-lane CNOT block:
  // even scalars: srcE = src89(src78(l)); odd scalars: srcO = srcE ^ 4.
  const int mE = (l3 & 4) ? (l3 ^ 2) : l3;
  const int sE = (mE & 2) ? (mE ^ 1) : mE;
  const int addrE = ((lane & ~7) | sE) << 2;
  const int addrO = addrE ^ 16;

  v2f w[64];

  // ---- load 784 cols via coalesced float4 -> LDS -> registers ------------
  #pragma unroll
  for (int h = 0; h < 2; ++h) {
    #pragma unroll
    for (int t = 0; t < 13; ++t) {
      int f = t * 64 + lane;
      if (f < 784) {
        int row = f / 98;
        int c4  = f - row * 98;
        float4 val = reinterpret_cast<const float4*>(
            x + (elemBase + row) * 784 + h * 392)[c4];
        reinterpret_cast<float4*>(&stage[wv][row][0])[c4] = val;
      }
    }
    __syncthreads();
    #pragma unroll
    for (int k = 0; k < 49; ++k) {
      float val = stage[wv][g][k * 8 + l3];
      int r = h * 49 + k;
      if (r & 1) w[r >> 1].y = val; else w[r >> 1].x = val;
    }
    __syncthreads();
  }
  #pragma unroll
  for (int u = 49; u < 64; ++u) w[u] = (v2f){0.f, 0.f};

  // ---- L2 normalize ------------------------------------------------------
  v2f acc2 = {0.f, 0.f};
  #pragma unroll
  for (int u = 0; u < 49; ++u) acc2 += w[u] * w[u];
  float nn = red8(acc2.x + acc2.y);
  float scl = 1.0f / sqrtf(nn);
  v2f scl2 = {scl, scl};
  #pragma unroll
  for (int u = 0; u < 49; ++u) w[u] *= scl2;

  // ---- 8 layers ----------------------------------------------------------
  #pragma unroll 1
  for (int l = 0; l < 8; ++l) {
    const float* cl = &csh[l * 20];

    // fused cross-lane CNOTs (6,7),(8,9),(7,8): one bpermute per scalar
    #pragma unroll
    for (int u = 0; u < 64; ++u) {
      w[u].x = bperm(addrE, w[u].x);
      w[u].y = bperm(addrO, w[u].y);
    }

    // RY q0 with the 6 reg-CNOTs folded into operand addressing
    {
      v2f cc = {cl[0], cl[0]}, ss = {cl[1], cl[1]};
      v2f nw[64];
      #pragma unroll
      for (int u = 0; u < 32; ++u) {
        const int p0 = phi(2 * u);
        const int p1 = phi(2 * u + 64);
        v2f a = w[p0 >> 1]; if (p0 & 1) a = __builtin_shufflevector(a, a, 1, 0);
        v2f b = w[p1 >> 1]; if (p1 & 1) b = __builtin_shufflevector(b, b, 1, 0);
        nw[u]      = cc * a - ss * b;
        nw[u + 32] = ss * a + cc * b;
      }
      #pragma unroll
      for (int u = 0; u < 64; ++u) w[u] = nw[u];
    }

    // RY q1..q5 (packed, stride Mw = M/2)
    { v2f cc = {cl[2],  cl[2]},  ss = {cl[3],  cl[3]};  ry_w<16>(w, cc, ss); }
    { v2f cc = {cl[4],  cl[4]},  ss = {cl[5],  cl[5]};  ry_w< 8>(w, cc, ss); }
    { v2f cc = {cl[6],  cl[6]},  ss = {cl[7],  cl[7]};  ry_w< 4>(w, cc, ss); }
    { v2f cc = {cl[8],  cl[8]},  ss = {cl[9],  cl[9]};  ry_w< 2>(w, cc, ss); }
    { v2f cc = {cl[10], cl[10]}, ss = {cl[11], cl[11]}; ry_w< 1>(w, cc, ss); }

    // RY q6 (within-float2 pair): out = A*(x,x) + B*(y,y), A=(c,s), B=(-s,c)
    {
      v2f A = {cl[12], cl[13]};
      v2f B = {-cl[13], cl[12]};
      #pragma unroll
      for (int u = 0; u < 64; ++u) {
        v2f lo = {w[u].x, w[u].x};
        v2f hi = {w[u].y, w[u].y};
        w[u] = A * lo + B * hi;
      }
    }

    // RY q7 (lane bit 2, partner via ds_swizzle xor4)
    {
      float c = cl[14], s = cl[15];
      float sn = (lane & 4) ? s : -s;
      v2f cc = {c, c}, ss2 = {sn, sn};
      #pragma unroll
      for (int u = 0; u < 64; ++u) {
        v2f p = { xl4(w[u].x), xl4(w[u].y) };
        w[u] = cc * w[u] + ss2 * p;
      }
    }
    // RY q8 (lane bit 1, partner via DPP xor2)
    {
      float c = cl[16], s = cl[17];
      float sn = (lane & 2) ? s : -s;
      v2f cc = {c, c}, ss2 = {sn, sn};
      #pragma unroll
      for (int u = 0; u < 64; ++u) {
        v2f p = { xl2(w[u].x), xl2(w[u].y) };
        w[u] = cc * w[u] + ss2 * p;
      }
    }
    // RY q9 (lane bit 0, partner via DPP xor1)
    {
      float c = cl[18], s = cl[19];
      float sn = (lane & 1) ? s : -s;
      v2f cc = {c, c}, ss2 = {sn, sn};
      #pragma unroll
      for (int u = 0; u < 64; ++u) {
        v2f p = { xl1(w[u].x), xl1(w[u].y) };
        w[u] = cc * w[u] + ss2 * p;
      }
    }
  }

  // ---- expectation values ------------------------------------------------
  #pragma unroll
  for (int u = 0; u < 64; ++u) w[u] *= w[u];   // probabilities

  float t[64];
  float a0 = 0.f, a1 = 0.f;
  #pragma unroll
  for (int u = 0; u < 64; ++u) {
    float d = w[u].x - w[u].y;
    if (u & 1) a1 += d; else a0 += d;
    t[u] = w[u].x + w[u].y;
  }
  float z[10];
  z[6] = red8(a0 + a1);
  z[5] = red8(tree_level<32>(t));
  z[4] = red8(tree_level<16>(t));
  z[3] = red8(tree_level< 8>(t));
  z[2] = red8(tree_level< 4>(t));
  z[1] = red8(tree_level< 2>(t));
  z[0] = red8(tree_level< 1>(t));
  float W = t[0];  // per-lane total probability
  { float u2 = W + xl1(W); u2 += xl2(u2); float tt = u2 - xl4(u2); z[7] = (lane & 4) ? -tt : tt; }
  { float u2 = W + xl1(W); float tt = u2 - xl2(u2); tt += xl4(tt); z[8] = (lane & 2) ? -tt : tt; }
  { float tt = W - xl1(W); tt += xl2(tt); tt += xl4(tt);           z[9] = (lane & 1) ? -tt : tt; }

  // ---- store -------------------------------------------------------------
  float o1 = z[0];
  #pragma unroll
  for (int j = 1; j < 8; ++j) o1 = (l3 == j) ? z[j] : o1;
  out[elem * 10 + l3] = o1;
  if (l3 < 2) out[elem * 10 + 8 + l3] = (l3 == 0) ? z[8] : z[9];
}

extern "C" void kernel_launch(void* const* d_in, const int* in_sizes, int n_in,
                              void* d_out, int out_size, void* d_ws, size_t ws_size,
                              hipStream_t stream) {
  const float* x      = (const float*)d_in[0];   // [16384, 784]
  const float* params = (const float*)d_in[1];   // [8, 10]
  float* out          = (float*)d_out;           // [16384, 10]
  (void)d_ws; (void)ws_size; (void)in_sizes; (void)n_in; (void)out_size;
  circuit_kernel<<<512, 256, 0, stream>>>(x, params, out);
}